// Round 5
// baseline (45282.639 us; speedup 1.0000x reference)
//
#include <hip/hip_runtime.h>
#include <cstdint>
#include <cstddef>

// ---------------------------------------------------------------------------
// Tacotron decoder, MI355X. Round 7: f16 weights + v_dot2_f32_f16 GEMVs.
// R4 datum: FETCH_SIZE == stream size -> weights already L2-resident; the
// 92us step is VALU (GEMV unpack+fma ~11us, tanh ~8us) + per-CU L2 port
// (~3.3MB/step ~22us) + latency chains, poorly overlapped (16 VALU per load).
// Fix: weights f16 in K-blocked [k/8][n][8] layout; activations mirrored as
// packed f16 in LDS; inner loop = 1 glb load + 1 ds_read_b128 + 4 fdot2
// (vs 1 load + 16 VALU). GEMV VALU ~4x down, 4-op dependent chains.
// Energy/context phases unchanged from R1 (fastest measured).
// ---------------------------------------------------------------------------

#define TDEC   250
#define BATCH  128

#define ALPHA_OFF  ((size_t)12800000)        // 128*1250*80 floats
#define WP_OFF     ((size_t)45568000)

// ---- ws byte offsets ----
#define WS_WACC_B   ((size_t)0)
#define WS_WGT_B    ((size_t)4096)
#define WGT_ELEMS   1658880
#define WS_KEYS_B   (WS_WGT_B + (size_t)WGT_ELEMS * 2)
#define WS_ENC_B    (WS_KEYS_B + (size_t)33554432 * 2)

// ---- weight offsets (f16 elems, K-blocked [k/8][N][8] layout) ----
#define OFF_PRE_W1   0          // 80x256
#define OFF_PRE_W2   20480      // 256x128
#define OFF_ATT_WG   53248      // 640x512
#define OFF_ATT_WC   380928     // 384x256 (x-part rows 0..383)
#define OFF_ATT_WCH  479232     // 256x256 (h-part rows 384..639)
#define OFF_ATTN_WQ  544768     // 256x256
#define OFF_DECI_W   610304     // 512x256
#define OFF_DEC1_WG  741376     // 512x512
#define OFF_DEC1_WC  1003520    // 256x256 (x-part)
#define OFF_DEC1_WCH 1069056    // 256x256 (h-part)
#define OFF_DEC2_WG  1134592    // 512x512
#define OFF_DEC2_WC  1396736    // 256x256
#define OFF_DEC2_WCH 1462272    // 256x256
#define OFF_OUT_WP   1527808    // 256x512 (padded from 256x400)

typedef _Float16 f16;
typedef f16 f16x2 __attribute__((ext_vector_type(2)));
typedef f16 f16x8 __attribute__((ext_vector_type(8)));

__device__ inline unsigned short f2bf(float f){
    unsigned int u = __float_as_uint(f);
    u = (u + 0x7fffu + ((u >> 16) & 1u)) >> 16;
    return (unsigned short)u;
}
__device__ inline float ftanh(float x){
    float e = __expf(2.f * x);
    return 1.f - 2.f * __builtin_amdgcn_rcpf(e + 1.f);
}
__device__ inline float fsig(float x){
    return __builtin_amdgcn_rcpf(1.f + __expf(-x));
}

__device__ inline float fdot2f(f16x2 a, f16x2 b, float c){
#if __has_builtin(__builtin_amdgcn_fdot2)
    return __builtin_amdgcn_fdot2(a, b, c, false);
#else
    return c + (float)a.x * (float)b.x + (float)a.y * (float)b.y;
#endif
}

// ---------------- f16 dot-GEMV: scratch[part*N+n] = x_part . W[:,n] --------
// W layout: [K/8][N][8] f16. Thread -> (n = tid&(N-1), part = tid>>log2N).
// Wave lanes n consecutive -> 16B x 64 = 1KB coalesced glb loads.
// All lanes of a wave share part -> LDS x reads broadcast (conflict-free).
template<int K, int N, int PARTS>
__device__ inline void gemv_dot(const f16* __restrict__ W,
                                const f16* __restrict__ xh,   // LDS, 16B aligned
                                float* __restrict__ scratch, int tid)
{
    constexpr int LGN = (N == 128) ? 7 : (N == 256) ? 8 : 9;
    constexpr int NT  = K / (8 * PARTS);          // f16x8 tiles per thread
    static_assert(NT * 8 * PARTS == K, "K must split into 8-elem tiles");
    static_assert(N * PARTS <= 1024, "too many threads");
    const int n    = tid & (N - 1);
    const int part = tid >> LGN;
    if (PARTS == (1024 >> LGN) || part < PARTS){
        const f16x8* Wp = (const f16x8*)W + (size_t)(part * NT) * N + n;
        const f16x8* xp = (const f16x8*)xh + part * NT;
        float acc = 0.f;
        #pragma unroll
        for (int t = 0; t < NT; t++){
            union { f16x8 v; f16x2 p[4]; } w, xv;
            w.v  = Wp[(size_t)t * N];
            xv.v = xp[t];
            acc = fdot2f(w.p[0], xv.p[0], acc);
            acc = fdot2f(w.p[1], xv.p[1], acc);
            acc = fdot2f(w.p[2], xv.p[2], acc);
            acc = fdot2f(w.p[3], xv.p[3], acc);
        }
        scratch[part * N + n] = acc;
    }
}

// ---------------- prep kernels ----------------------------------------------
__global__ void k_cvt_flat(const float* __restrict__ src, unsigned short* __restrict__ dst, int n){
    int i = blockIdx.x * 256 + threadIdx.x;
    if (i < n) dst[i] = f2bf(src[i]);
}
// fp32 [K][srcN] (rows row0..row0+K) -> f16 K-blocked [k/8][N][8], pad n>=srcN
__global__ void k_cvt_dot(const float* __restrict__ src, f16* __restrict__ dst,
                          int K, int N, int srcN, int row0){
    int i = blockIdx.x * 256 + threadIdx.x;
    if (i >= K * N) return;
    int k = i / N, n = i - k * N;
    float v = (n < srcN) ? src[(size_t)(row0 + k) * srcN + n] : 0.f;
    dst[((size_t)(k >> 3) * N + n) * 8 + (k & 7)] = (f16)v;
}

// ---------------- K1: keys_T[b][d][t] = bf16(enc @ Wk + bk) -----------------
__global__ __launch_bounds__(256) void k_keys(const float* __restrict__ enc,
                                              const float* __restrict__ Wk,
                                              const float* __restrict__ bk,
                                              unsigned short* __restrict__ keysT)
{
    __shared__ __align__(16) float Wt[64 * 256];   // [kk][d]
    __shared__ float At[64 * 64];                  // [r][kk]
    __shared__ unsigned short tileT[256 * 68];     // [d][t_loc], pad 68
    const int tid = threadIdx.x;
    const size_t row0 = (size_t)blockIdx.x * 64;
    const int dq = tid & 63;
    const int rg = tid >> 6;

    float4 acc[16];
    #pragma unroll
    for (int i = 0; i < 16; i++) acc[i] = float4{0.f, 0.f, 0.f, 0.f};

    for (int k0 = 0; k0 < 256; k0 += 64){
        __syncthreads();
        #pragma unroll
        for (int i = 0; i < 64; i++)
            Wt[i * 256 + tid] = Wk[(size_t)(k0 + i) * 256 + tid];
        #pragma unroll
        for (int i = 0; i < 16; i++){
            int idx = tid + i * 256;
            int r = idx >> 6, kk = idx & 63;
            At[idx] = enc[(row0 + r) * 256 + k0 + kk];
        }
        __syncthreads();
        for (int kk = 0; kk < 64; kk++){
            float4 w = ((const float4*)Wt)[kk * 64 + dq];
            #pragma unroll
            for (int rr = 0; rr < 16; rr++){
                float a = At[(rg * 16 + rr) * 64 + kk];
                acc[rr].x += a * w.x; acc[rr].y += a * w.y;
                acc[rr].z += a * w.z; acc[rr].w += a * w.w;
            }
        }
    }
    float4 bb = ((const float4*)bk)[dq];
    __syncthreads();
    #pragma unroll
    for (int rr = 0; rr < 16; rr++){
        int t_loc = rg * 16 + rr;
        #pragma unroll
        for (int c = 0; c < 4; c++){
            float val = (&acc[rr].x)[c] + (&bb.x)[c];
            int d = dq * 4 + c;
            tileT[d * 68 + t_loc] = f2bf(val);
        }
    }
    __syncthreads();
    const int b_ = (int)(row0 >> 10);
    const int t0 = (int)(row0 & 1023);
    #pragma unroll
    for (int i = 0; i < 16; i++){
        int flat = tid + i * 256;
        int d = flat >> 4, tq = flat & 15;
        ushort4 v = *(const ushort4*)&tileT[d * 68 + tq * 4];
        *(ushort4*)&keysT[(((size_t)(b_ * 256 + d)) << 10) + t0 + tq * 4] = v;
    }
}

// ---------------- K2: main recurrent kernel, block = batch row b ------------
struct KParams {
    const int *imask; const float *inp_att; const float *style_tok;
    const float *pre_b1, *pre_b2, *att_bg, *att_bc, *attn_bq, *attn_v;
    const float *deci_b, *dec1_bg, *dec1_bc, *dec2_bg, *dec2_bc, *out_b;
    const f16 *wgt;                 // f16 weight block (K-blocked)
    const unsigned short *keysT;    // [128][256][1024] bf16
    const unsigned short *encb;     // [128][1024][256] bf16
    float *wacc; float *out;
};

__global__ __launch_bounds__(1024, 1) void k_main(KParams p)
{
    __shared__ __align__(16) float scr [8192];     // energy/context + big GEMVs
    __shared__ __align__(16) float scr2[2048];     // small GEMV partials
    __shared__ float e_l[1024];
    __shared__ float g_l[512], cx_l[256];
    __shared__ float h_att[256], h1[256], h2[256], dci[256], o1_l[256];
    __shared__ float stylel[256], astylel[256], v_l[256], q_l[256];
    __shared__ float red[16];
    // packed-f16 activation mirrors (GEMV inputs)
    __shared__ __align__(16) f16 xah[640];    // [ctx 0:256 | p 256:384 | h_att 384:640]
    __shared__ __align__(16) f16 xdh[512];    // [h_att, wctx]
    __shared__ __align__(16) f16 xgh[512];    // [dci,h1] then [o1,h2]
    __shared__ __align__(16) f16 xrh[256];    // r*h (att)
    __shared__ __align__(16) f16 xr2h[256];   // r*h (dec1/dec2)
    __shared__ __align__(16) f16 o2h[256];
    __shared__ __align__(16) f16 p1h[256];
    __shared__ __align__(16) f16 lastoh[80];

    const int tid = threadIdx.x;
    const int b   = blockIdx.x;
    const int mlen = p.imask[b];          // 1..1024
    const f16* W = p.wgt;

    if (tid < 256){
        h_att[tid] = 0.f; h1[tid] = 0.f; h2[tid] = 0.f;
        float s = 0.f;
        #pragma unroll
        for (int k = 0; k < 10; k++) s += p.inp_att[b * 10 + k] * p.style_tok[k * 256 + tid];
        stylel[tid] = s; astylel[tid] = fabsf(s);
        v_l[tid] = p.attn_v[tid];
        xah[tid] = (f16)0.f;          // ctx = 0
        xah[384 + tid] = (f16)0.f;    // h_att = 0
    }
    if (tid < 80) lastoh[tid] = (f16)0.f;
    __syncthreads();

    for (int s = 0; s < TDEC; s++){
        // ---- P1: prenet1 (80 -> 256, relu) ----
        gemv_dot<80, 256, 2>(W + OFF_PRE_W1, lastoh, scr2, tid);
        __syncthreads();
        if (tid < 256)
            p1h[tid] = (f16)fmaxf(p.pre_b1[tid] + scr2[tid] + scr2[256 + tid], 0.f);
        __syncthreads();

        // ---- P2: prenet2 (256 -> 128, relu) -> xah[256..383] ----
        gemv_dot<256, 128, 8>(W + OFF_PRE_W2, p1h, scr2, tid);
        __syncthreads();
        if (tid < 128){
            float sv = p.pre_b2[tid];
            #pragma unroll
            for (int q = 0; q < 8; q++) sv += scr2[q * 128 + tid];
            xah[256 + tid] = (f16)fmaxf(sv, 0.f);
        }
        __syncthreads();

        // ---- P3: att GRU A: g = sig(xa@Wg), cx = bc + xa[0:384]@Wc_x ----
        gemv_dot<640, 512, 2>(W + OFF_ATT_WG, xah, scr,  tid);
        gemv_dot<384, 256, 4>(W + OFF_ATT_WC, xah, scr2, tid);
        __syncthreads();
        if (tid < 512){
            float g = fsig(p.att_bg[tid] + scr[tid] + scr[512 + tid]);
            g_l[tid] = g;
            if (tid < 256) xrh[tid] = (f16)(g * h_att[tid]);    // r*h
        } else if (tid < 768){
            int n = tid - 512;
            float sv = p.att_bc[n];
            #pragma unroll
            for (int q = 0; q < 4; q++) sv += scr2[q * 256 + n];
            cx_l[n] = sv;
        }
        __syncthreads();

        // ---- P4: c = tanh(cx + (r*h)@Wc_h); h_att update ----
        gemv_dot<256, 256, 4>(W + OFF_ATT_WCH, xrh, scr2, tid);
        __syncthreads();
        if (tid < 256){
            float sv = cx_l[tid];
            #pragma unroll
            for (int q = 0; q < 4; q++) sv += scr2[q * 256 + tid];
            float c = ftanh(sv);
            float u = g_l[256 + tid];
            float h = u * h_att[tid] + (1.f - u) * c;
            h_att[tid] = h;
            xah[384 + tid] = (f16)h;    // next step's P3 + this step's P5
            xdh[tid] = (f16)h;          // P8
        }
        __syncthreads();

        // ---- P5: q = h_att @ Wq + bq ----
        gemv_dot<256, 256, 4>(W + OFF_ATTN_WQ, xah + 384, scr2, tid);
        __syncthreads();
        if (tid < 256){
            float sv = p.attn_bq[tid];
            #pragma unroll
            for (int q = 0; q < 4; q++) sv += scr2[q * 256 + tid];
            q_l[tid] = sv;
        }
        __syncthreads();

        // ---- P6: energy e[t] = sum_d tanh(keysT[d][t]+q[d])*v[d]; softmax
        // (max-free: |e| <= sum|v| ~ 10, exp safe in fp32)
        {
            const int tc   = tid & 127;
            const int part = tid >> 7;
            float acc0=0.f,acc1=0.f,acc2=0.f,acc3=0.f,acc4=0.f,acc5=0.f,acc6=0.f,acc7=0.f;
            if (tc * 8 < mlen){
                const unsigned short* kp = p.keysT + (((size_t)b) << 18)
                                         + ((size_t)(part * 32) << 10) + tc * 8;
                #pragma unroll 16
                for (int dd = 0; dd < 32; dd++){
                    uint4 kv = *(const uint4*)(kp + ((size_t)dd << 10));
                    int d = part * 32 + dd;
                    float qd = q_l[d], vd = v_l[d];
                    acc0 = fmaf(ftanh(__uint_as_float(kv.x << 16)         + qd), vd, acc0);
                    acc1 = fmaf(ftanh(__uint_as_float(kv.x & 0xffff0000u) + qd), vd, acc1);
                    acc2 = fmaf(ftanh(__uint_as_float(kv.y << 16)         + qd), vd, acc2);
                    acc3 = fmaf(ftanh(__uint_as_float(kv.y & 0xffff0000u) + qd), vd, acc3);
                    acc4 = fmaf(ftanh(__uint_as_float(kv.z << 16)         + qd), vd, acc4);
                    acc5 = fmaf(ftanh(__uint_as_float(kv.z & 0xffff0000u) + qd), vd, acc5);
                    acc6 = fmaf(ftanh(__uint_as_float(kv.w << 16)         + qd), vd, acc6);
                    acc7 = fmaf(ftanh(__uint_as_float(kv.w & 0xffff0000u) + qd), vd, acc7);
                }
            }
            float4* s4 = (float4*)(scr + part * 1024 + tc * 8);
            s4[0] = float4{acc0, acc1, acc2, acc3};
            s4[1] = float4{acc4, acc5, acc6, acc7};
        }
        __syncthreads();
        float av = 0.f;
        if (tid < mlen){
            float s8 = 0.f;
            #pragma unroll
            for (int pp = 0; pp < 8; pp++) s8 += scr[pp * 1024 + tid];
            av = __expf(s8);
        }
        {   // block sum: per-wave shuffle -> 16 LDS -> broadcast sum
            float ws = av;
            #pragma unroll
            for (int off = 32; off; off >>= 1) ws += __shfl_xor(ws, off, 64);
            if ((tid & 63) == 0) red[tid >> 6] = ws;
        }
        __syncthreads();
        {
            float tot = 0.f;
            #pragma unroll
            for (int i = 0; i < 16; i++) tot += red[i];
            float alpha = av * __builtin_amdgcn_rcpf(tot);
            e_l[tid] = alpha;
            __builtin_nontemporal_store(alpha,
                &p.out[ALPHA_OFF + (size_t)s * 131072 + ((size_t)b << 10) + tid]);
        }
        __syncthreads();

        // ---- P7: context ctx[d] = sum_t alpha[t]*enc[t][d] ----
        {
            const int dc = tid & 31;
            const int tp = tid >> 5;
            float acc0=0.f,acc1=0.f,acc2=0.f,acc3=0.f,acc4=0.f,acc5=0.f,acc6=0.f,acc7=0.f;
            const unsigned short* er = p.encb + (((size_t)b) << 18) + dc * 8;
            #pragma unroll 8
            for (int t = tp; t < mlen; t += 32){
                uint4 ev4 = *(const uint4*)(er + ((size_t)t << 8));
                float al = e_l[t];
                acc0 = fmaf(al, __uint_as_float(ev4.x << 16),         acc0);
                acc1 = fmaf(al, __uint_as_float(ev4.x & 0xffff0000u), acc1);
                acc2 = fmaf(al, __uint_as_float(ev4.y << 16),         acc2);
                acc3 = fmaf(al, __uint_as_float(ev4.y & 0xffff0000u), acc3);
                acc4 = fmaf(al, __uint_as_float(ev4.z << 16),         acc4);
                acc5 = fmaf(al, __uint_as_float(ev4.z & 0xffff0000u), acc5);
                acc6 = fmaf(al, __uint_as_float(ev4.w << 16),         acc6);
                acc7 = fmaf(al, __uint_as_float(ev4.w & 0xffff0000u), acc7);
            }
            float4* s4 = (float4*)(scr + tp * 256 + dc * 8);
            s4[0] = float4{acc0, acc1, acc2, acc3};
            s4[1] = float4{acc4, acc5, acc6, acc7};
        }
        __syncthreads();
        if (tid < 256){
            float cs = 0.f;
            #pragma unroll
            for (int pp = 0; pp < 32; pp++) cs += scr[pp * 256 + tid];
            xah[tid] = (f16)cs;                       // ctx, next step's P3
            xdh[256 + tid] = (f16)(cs + stylel[tid]); // wctx for P8
            float wpv = astylel[tid] * __builtin_amdgcn_rcpf(fabsf(cs) + astylel[tid]);
            #pragma unroll
            for (int off = 32; off; off >>= 1) wpv += __shfl_xor(wpv, off, 64);
            if ((tid & 63) == 0) atomicAdd(&p.wacc[s], wpv);
        }
        __syncthreads();

        // ---- P8: dec_in = [h_att, wctx] @ deci_W + b ----
        gemv_dot<512, 256, 4>(W + OFF_DECI_W, xdh, scr2, tid);
        __syncthreads();
        if (tid < 256){
            float sv = p.deci_b[tid];
            #pragma unroll
            for (int q = 0; q < 4; q++) sv += scr2[q * 256 + tid];
            dci[tid] = sv;
            xgh[tid] = (f16)sv; xgh[256 + tid] = (f16)h1[tid];
        }
        __syncthreads();

        // ---- P9: dec1 A: g1, cx1 ----
        gemv_dot<512, 512, 2>(W + OFF_DEC1_WG, xgh, scr,  tid);
        gemv_dot<256, 256, 4>(W + OFF_DEC1_WC, xgh, scr2, tid);
        __syncthreads();
        if (tid < 512){
            float g = fsig(p.dec1_bg[tid] + scr[tid] + scr[512 + tid]);
            g_l[tid] = g;
            if (tid < 256) xr2h[tid] = (f16)(g * h1[tid]);
        } else if (tid < 768){
            int n = tid - 512;
            float sv = p.dec1_bc[n];
            #pragma unroll
            for (int q = 0; q < 4; q++) sv += scr2[q * 256 + n];
            cx_l[n] = sv;
        }
        __syncthreads();

        // ---- P10: dec1 B ----
        gemv_dot<256, 256, 4>(W + OFF_DEC1_WCH, xr2h, scr2, tid);
        __syncthreads();
        if (tid < 256){
            float sv = cx_l[tid];
            #pragma unroll
            for (int q = 0; q < 4; q++) sv += scr2[q * 256 + tid];
            float c = ftanh(sv);
            float u = g_l[256 + tid];
            float hn = u * h1[tid] + (1.f - u) * c;
            h1[tid] = hn;
            float o1 = hn + dci[tid];
            o1_l[tid] = o1;
            xgh[tid] = (f16)o1; xgh[256 + tid] = (f16)h2[tid];
        }
        __syncthreads();

        // ---- P11: dec2 A ----
        gemv_dot<512, 512, 2>(W + OFF_DEC2_WG, xgh, scr,  tid);
        gemv_dot<256, 256, 4>(W + OFF_DEC2_WC, xgh, scr2, tid);
        __syncthreads();
        if (tid < 512){
            float g = fsig(p.dec2_bg[tid] + scr[tid] + scr[512 + tid]);
            g_l[tid] = g;
            if (tid < 256) xr2h[tid] = (f16)(g * h2[tid]);
        } else if (tid < 768){
            int n = tid - 512;
            float sv = p.dec2_bc[n];
            #pragma unroll
            for (int q = 0; q < 4; q++) sv += scr2[q * 256 + n];
            cx_l[n] = sv;
        }
        __syncthreads();

        // ---- P12: dec2 B ----
        gemv_dot<256, 256, 4>(W + OFF_DEC2_WCH, xr2h, scr2, tid);
        __syncthreads();
        if (tid < 256){
            float sv = cx_l[tid];
            #pragma unroll
            for (int q = 0; q < 4; q++) sv += scr2[q * 256 + tid];
            float c = ftanh(sv);
            float u = g_l[256 + tid];
            float hn = u * h2[tid] + (1.f - u) * c;
            h2[tid] = hn;
            o2h[tid] = (f16)(hn + o1_l[tid]);
        }
        __syncthreads();

        // ---- P13: output dense (256 -> 400 via padded 512) ----
        gemv_dot<256, 512, 2>(W + OFF_OUT_WP, o2h, scr, tid);
        __syncthreads();
        if (tid < 400){
            float val = p.out_b[tid] + scr[tid] + scr[512 + tid];
            __builtin_nontemporal_store(val,
                &p.out[(size_t)b * 100000 + (size_t)s * 400 + tid]);
            if (tid >= 320) lastoh[tid - 320] = (f16)val;
        }
        __syncthreads();
    }
}

// ---------------- K3: finalize weight_pers ----------------------------------
__global__ void k_final(const float* __restrict__ wacc, float* __restrict__ out)
{
    int i = threadIdx.x;
    if (i < TDEC) out[WP_OFF + i] = wacc[i] * (1.0f / 32768.0f);
}

// ---------------------------------------------------------------------------
extern "C" void kernel_launch(void* const* d_in, const int* in_sizes, int n_in,
                              void* d_out, int out_size, void* d_ws, size_t ws_size,
                              hipStream_t stream)
{
    const float* enc        = (const float*)d_in[0];
    const int*   imask      = (const int*)  d_in[1];
    const float* inp_att    = (const float*)d_in[2];
    const float* style_tok  = (const float*)d_in[3];
    const float* pre_W1     = (const float*)d_in[4];
    const float* pre_b1     = (const float*)d_in[5];
    const float* pre_W2     = (const float*)d_in[6];
    const float* pre_b2     = (const float*)d_in[7];
    const float* att_Wg     = (const float*)d_in[8];
    const float* att_bg     = (const float*)d_in[9];
    const float* att_Wc     = (const float*)d_in[10];
    const float* att_bc     = (const float*)d_in[11];
    const float* attn_Wk    = (const float*)d_in[12];
    const float* attn_bk    = (const float*)d_in[13];
    const float* attn_Wq    = (const float*)d_in[14];
    const float* attn_bq    = (const float*)d_in[15];
    const float* attn_v     = (const float*)d_in[16];
    const float* deci_W     = (const float*)d_in[17];
    const float* deci_b     = (const float*)d_in[18];
    const float* dec1_Wg    = (const float*)d_in[19];
    const float* dec1_bg    = (const float*)d_in[20];
    const float* dec1_Wc    = (const float*)d_in[21];
    const float* dec1_bc    = (const float*)d_in[22];
    const float* dec2_Wg    = (const float*)d_in[23];
    const float* dec2_bg    = (const float*)d_in[24];
    const float* dec2_Wc    = (const float*)d_in[25];
    const float* dec2_bc    = (const float*)d_in[26];
    const float* out_W      = (const float*)d_in[27];
    const float* out_b      = (const float*)d_in[28];

    float*          wacc  = (float*)((char*)d_ws + WS_WACC_B);
    f16*            wgt   = (f16*)  ((char*)d_ws + WS_WGT_B);
    unsigned short* keysT = (unsigned short*)((char*)d_ws + WS_KEYS_B);
    unsigned short* encb  = (unsigned short*)((char*)d_ws + WS_ENC_B);
    float* out = (float*)d_out;

    hipMemsetAsync(d_ws, 0, 1024, stream);

    // ---- weight conversions (f16, K-blocked layout) ----
    auto cvtd = [&](const float* src, size_t off, int K, int N, int srcN, int row0){
        k_cvt_dot<<<(K * N + 255) / 256, 256, 0, stream>>>(src, wgt + off, K, N, srcN, row0);
    };
    cvtd(pre_W1,  OFF_PRE_W1,    80, 256, 256, 0);
    cvtd(pre_W2,  OFF_PRE_W2,   256, 128, 128, 0);
    cvtd(att_Wg,  OFF_ATT_WG,   640, 512, 512, 0);
    cvtd(att_Wc,  OFF_ATT_WC,   384, 256, 256, 0);
    cvtd(att_Wc,  OFF_ATT_WCH,  256, 256, 256, 384);
    cvtd(attn_Wq, OFF_ATTN_WQ,  256, 256, 256, 0);
    cvtd(deci_W,  OFF_DECI_W,   512, 256, 256, 0);
    cvtd(dec1_Wg, OFF_DEC1_WG,  512, 512, 512, 0);
    cvtd(dec1_Wc, OFF_DEC1_WC,  256, 256, 256, 0);
    cvtd(dec1_Wc, OFF_DEC1_WCH, 256, 256, 256, 256);
    cvtd(dec2_Wg, OFF_DEC2_WG,  512, 512, 512, 0);
    cvtd(dec2_Wc, OFF_DEC2_WC,  256, 256, 256, 0);
    cvtd(dec2_Wc, OFF_DEC2_WCH, 256, 256, 256, 256);
    cvtd(out_W,   OFF_OUT_WP,   256, 512, 400, 0);

    // ---- enc -> bf16 ----
    k_cvt_flat<<<(33554432 + 255) / 256, 256, 0, stream>>>(enc, encb, 33554432);

    // ---- keys (transposed bf16) ----
    k_keys<<<2048, 256, 0, stream>>>(enc, attn_Wk, attn_bk, keysT);

    KParams kp{imask, inp_att, style_tok,
               pre_b1, pre_b2, att_bg, att_bc, attn_bq, attn_v,
               deci_b, dec1_bg, dec1_bc, dec2_bg, dec2_bc, out_b,
               wgt, keysT, encb, wacc, out};
    k_main<<<BATCH, 1024, 0, stream>>>(kp);

    k_final<<<1, 256, 0, stream>>>(wacc, out);
}

// Round 6
// 21106.839 us; speedup vs baseline: 2.1454x; 2.1454x over previous
//
#include <hip/hip_runtime.h>
#include <cstdint>
#include <cstddef>

// ---------------------------------------------------------------------------
// Tacotron decoder, MI355X. Round 8: R1 memory structure restored exactly
// (row-major [K][N] weights, same uint4 lane pattern -> L2-resident weights,
// FETCH ~= streams only). Changes vs R1 are ALU/idle-thread only:
//  A. weights f16 (same offsets/addresses): extract via (float)h + fmaf ->
//     v_fma_mix_f32 (8 ops / 8 MACs vs bf16's 16). Accuracy improves.
//  B. energy phase: mlen<=512 uses 64 t-chunks x 16 d-parts so all 1024
//     threads stream keysT (old mapping idled >=half the block).
// R5 lesson: K-blocked layout broke inter-block L2 reuse (+30GB HBM fetch).
// ---------------------------------------------------------------------------

#define TDEC   250
#define BATCH  128

#define ALPHA_OFF  ((size_t)12800000)        // 128*1250*80 floats
#define WP_OFF     ((size_t)45568000)

// ---- ws byte offsets ----
#define WS_WACC_B   ((size_t)0)
#define WS_WGT_B    ((size_t)4096)
#define WGT_ELEMS   1658880
#define WS_KEYS_B   (WS_WGT_B + (size_t)WGT_ELEMS * 2)
#define WS_ENC_B    (WS_KEYS_B + (size_t)33554432 * 2)

// ---- weight offsets (f16 elems, row-major [K][N]) ----
#define OFF_PRE_W1   0          // 80x256
#define OFF_PRE_W2   20480      // 256x128
#define OFF_ATT_WG   53248      // 640x512
#define OFF_ATT_WC   380928     // 640x256 (rows 0..383 = x-part)
#define OFF_ATT_WCH  479232     // rows 384..639 (r*h part)
#define OFF_ATTN_WQ  544768     // 256x256
#define OFF_DECI_W   610304     // 512x256
#define OFF_DEC1_WG  741376     // 512x512
#define OFF_DEC1_WC  1003520    // 512x256 (rows 0..255 = x-part)
#define OFF_DEC1_WCH 1069056    // rows 256..511
#define OFF_DEC2_WG  1134592    // 512x512
#define OFF_DEC2_WC  1396736    // 512x256
#define OFF_DEC2_WCH 1462272    // rows 256..511
#define OFF_OUT_WP   1527808    // 256x512 (padded from 256x400)

typedef _Float16 f16;
typedef f16 f16x8 __attribute__((ext_vector_type(8)));

__device__ inline unsigned short f2bf(float f){
    unsigned int u = __float_as_uint(f);
    u = (u + 0x7fffu + ((u >> 16) & 1u)) >> 16;
    return (unsigned short)u;
}
__device__ inline float ftanh(float x){
    float e = __expf(2.f * x);
    return 1.f - 2.f * __builtin_amdgcn_rcpf(e + 1.f);
}
__device__ inline float fsig(float x){
    return __builtin_amdgcn_rcpf(1.f + __expf(-x));
}

// ---------------- f16 GEMV partials: scratch[part][N] = x_part @ W_part ----
// Memory pattern IDENTICAL to R1 bf16 version (same byte addresses); only
// the unpack differs: (float)f16 + fmaf -> v_fma_mix_f32.
template<int K, int N, int PARTS>
__device__ inline void gemv_part(const f16* __restrict__ W,
                                 const float* __restrict__ x,
                                 float* __restrict__ scratch, int tid)
{
    constexpr int CH   = N / 8;
    constexpr int LG   = (CH == 16) ? 4 : (CH == 32) ? 5 : 6;
    constexpr int KCNT = K / PARTS;
    static_assert(KCNT * PARTS == K, "K must divide");
    static_assert(CH * PARTS <= 1024, "too many threads");
    const int chunk = tid & (CH - 1);
    const int part  = tid >> LG;
    if (PARTS == (1024 >> LG) || part < PARTS){
        const f16x8* Wp = (const f16x8*)W + (size_t)(part * KCNT) * (N / 8) + chunk;
        const float* xp = x + part * KCNT;
        float a0=0.f,a1=0.f,a2=0.f,a3=0.f,a4=0.f,a5=0.f,a6=0.f,a7=0.f;
        #pragma unroll 8
        for (int k = 0; k < KCNT; k++){
            f16x8 w = Wp[(size_t)k * (N / 8)];
            float xv = xp[k];
            a0 = fmaf((float)w[0], xv, a0);
            a1 = fmaf((float)w[1], xv, a1);
            a2 = fmaf((float)w[2], xv, a2);
            a3 = fmaf((float)w[3], xv, a3);
            a4 = fmaf((float)w[4], xv, a4);
            a5 = fmaf((float)w[5], xv, a5);
            a6 = fmaf((float)w[6], xv, a6);
            a7 = fmaf((float)w[7], xv, a7);
        }
        float4* s4 = (float4*)(scratch + part * N + chunk * 8);
        s4[0] = float4{a0, a1, a2, a3};
        s4[1] = float4{a4, a5, a6, a7};
    }
}

template<int N, int PARTS>
__device__ inline float red_parts(const float* __restrict__ scratch, int n){
    float s = 0.f;
    #pragma unroll
    for (int p = 0; p < PARTS; p++) s += scratch[p * N + n];
    return s;
}

// ---------------- prep: fp32 -> bf16 / f16 conversions -----------------------
__global__ void k_cvt_flat(const float* __restrict__ src, unsigned short* __restrict__ dst, int n){
    int i = blockIdx.x * 256 + threadIdx.x;
    if (i < n) dst[i] = f2bf(src[i]);
}
__global__ void k_cvt_flat16(const float* __restrict__ src, f16* __restrict__ dst, int n){
    int i = blockIdx.x * 256 + threadIdx.x;
    if (i < n) dst[i] = (f16)src[i];
}
__global__ void k_cvt_pad16(const float* __restrict__ src, f16* __restrict__ dst){
    int i = blockIdx.x * 256 + threadIdx.x;   // i < 256*512
    int k = i >> 9, n = i & 511;
    dst[i] = (n < 400) ? (f16)src[k * 400 + n] : (f16)0.f;
}

// ---------------- K1: keys_T[b][d][t] = bf16(enc @ Wk + bk) -----------------
__global__ __launch_bounds__(256) void k_keys(const float* __restrict__ enc,
                                              const float* __restrict__ Wk,
                                              const float* __restrict__ bk,
                                              unsigned short* __restrict__ keysT)
{
    __shared__ __align__(16) float Wt[64 * 256];   // [kk][d]
    __shared__ float At[64 * 64];                  // [r][kk]
    __shared__ unsigned short tileT[256 * 68];     // [d][t_loc], pad 68
    const int tid = threadIdx.x;
    const size_t row0 = (size_t)blockIdx.x * 64;
    const int dq = tid & 63;
    const int rg = tid >> 6;

    float4 acc[16];
    #pragma unroll
    for (int i = 0; i < 16; i++) acc[i] = float4{0.f, 0.f, 0.f, 0.f};

    for (int k0 = 0; k0 < 256; k0 += 64){
        __syncthreads();
        #pragma unroll
        for (int i = 0; i < 64; i++)
            Wt[i * 256 + tid] = Wk[(size_t)(k0 + i) * 256 + tid];
        #pragma unroll
        for (int i = 0; i < 16; i++){
            int idx = tid + i * 256;
            int r = idx >> 6, kk = idx & 63;
            At[idx] = enc[(row0 + r) * 256 + k0 + kk];
        }
        __syncthreads();
        for (int kk = 0; kk < 64; kk++){
            float4 w = ((const float4*)Wt)[kk * 64 + dq];
            #pragma unroll
            for (int rr = 0; rr < 16; rr++){
                float a = At[(rg * 16 + rr) * 64 + kk];
                acc[rr].x += a * w.x; acc[rr].y += a * w.y;
                acc[rr].z += a * w.z; acc[rr].w += a * w.w;
            }
        }
    }
    float4 bb = ((const float4*)bk)[dq];
    __syncthreads();
    #pragma unroll
    for (int rr = 0; rr < 16; rr++){
        int t_loc = rg * 16 + rr;
        #pragma unroll
        for (int c = 0; c < 4; c++){
            float val = (&acc[rr].x)[c] + (&bb.x)[c];
            int d = dq * 4 + c;
            tileT[d * 68 + t_loc] = f2bf(val);
        }
    }
    __syncthreads();
    const int b_ = (int)(row0 >> 10);
    const int t0 = (int)(row0 & 1023);
    #pragma unroll
    for (int i = 0; i < 16; i++){
        int flat = tid + i * 256;
        int d = flat >> 4, tq = flat & 15;
        ushort4 v = *(const ushort4*)&tileT[d * 68 + tq * 4];
        *(ushort4*)&keysT[(((size_t)(b_ * 256 + d)) << 10) + t0 + tq * 4] = v;
    }
}

// ---------------- K2: main recurrent kernel, block = batch row b ------------
struct KParams {
    const int *imask; const float *inp_att; const float *style_tok;
    const float *pre_b1, *pre_b2, *att_bg, *att_bc, *attn_bq, *attn_v;
    const float *deci_b, *dec1_bg, *dec1_bc, *dec2_bg, *dec2_bc, *out_b;
    const f16 *wgt;                 // f16 weight block (row-major)
    const unsigned short *keysT;    // [128][256][1024] bf16
    const unsigned short *encb;     // [128][1024][256] bf16
    float *wacc; float *out;
};

__global__ __launch_bounds__(1024, 1) void k_main(KParams p)
{
    __shared__ __align__(16) float scr [8192];     // GEMV/attention partials
    __shared__ __align__(16) float scr2[8192];     // second partial buffer
    __shared__ float xa[640];                       // [ctx, p, h_att] (att GRU in)
    __shared__ float xg[512];                       // [x, h] (dec GRU in)
    __shared__ float xr[256];                       // r*h
    __shared__ float xd[512];                       // [h_att, wctx]
    __shared__ float g_l[512], cx_l[256];
    __shared__ float h_att[256], h1[256], h2[256];
    __shared__ float p1_l[256], dci[256], o1_l[256], o2_l[256];
    __shared__ float stylel[256], astylel[256], v_l[256], q_l[256];
    __shared__ float e_l[1024];
    __shared__ float last_o[80];
    __shared__ float red[16];

    const int tid = threadIdx.x;
    const int b   = blockIdx.x;
    const int mlen = p.imask[b];          // 1..1024
    const f16* W = p.wgt;

    if (tid < 256){
        h_att[tid] = 0.f; h1[tid] = 0.f; h2[tid] = 0.f;
        float s = 0.f;
        #pragma unroll
        for (int k = 0; k < 10; k++) s += p.inp_att[b * 10 + k] * p.style_tok[k * 256 + tid];
        stylel[tid] = s; astylel[tid] = fabsf(s);
        v_l[tid] = p.attn_v[tid];
        xa[tid] = 0.f;            // ctx = 0
        xa[384 + tid] = 0.f;      // h_att = 0
    }
    if (tid < 80) last_o[tid] = 0.f;
    __syncthreads();

    const bool msmall = (mlen <= 512);

    for (int s = 0; s < TDEC; s++){
        // ---- P1: prenet1 (80 -> 256, relu) ----
        gemv_part<80, 256, 16>(W + OFF_PRE_W1, last_o, scr, tid);
        __syncthreads();
        if (tid < 256)
            p1_l[tid] = fmaxf(p.pre_b1[tid] + red_parts<256,16>(scr, tid), 0.f);
        __syncthreads();

        // ---- P2: prenet2 (256 -> 128, relu) -> xa[256..383] ----
        gemv_part<256, 128, 64>(W + OFF_PRE_W2, p1_l, scr, tid);
        __syncthreads();
        if (tid < 128)
            xa[256 + tid] = fmaxf(p.pre_b2[tid] + red_parts<128,64>(scr, tid), 0.f);
        __syncthreads();

        // ---- P3: att GRU phase A: g = sig(xa@Wg), cx = bc + xa[0:384]@Wc_x
        gemv_part<640, 512, 16>(W + OFF_ATT_WG, xa, scr,  tid);
        gemv_part<384, 256, 32>(W + OFF_ATT_WC, xa, scr2, tid);
        __syncthreads();
        if (tid < 512){
            float g = fsig(p.att_bg[tid] + red_parts<512,16>(scr, tid));
            g_l[tid] = g;
            if (tid < 256) xr[tid] = g * h_att[tid];        // r*h
        } else if (tid < 768){
            int n = tid - 512;
            cx_l[n] = p.att_bc[n] + red_parts<256,32>(scr2, n);
        }
        __syncthreads();

        // ---- P4: att GRU phase B: c = tanh(cx + (r*h)@Wc_h); h update ----
        gemv_part<256, 256, 32>(W + OFF_ATT_WCH, xr, scr, tid);
        __syncthreads();
        if (tid < 256){
            float c = ftanh(cx_l[tid] + red_parts<256,32>(scr, tid));
            float u = g_l[256 + tid];
            float h = u * h_att[tid] + (1.f - u) * c;
            h_att[tid] = h;
            xa[384 + tid] = h;     // for next step's P3
            xd[tid] = h;           // for P8 (deci)
        }
        __syncthreads();

        // ---- P5: q = h_att @ Wq + bq ----
        gemv_part<256, 256, 32>(W + OFF_ATTN_WQ, h_att, scr, tid);
        __syncthreads();
        if (tid < 256) q_l[tid] = p.attn_bq[tid] + red_parts<256,32>(scr, tid);
        __syncthreads();

        // ---- P6: energy e[t] = sum_d tanh(keysT[d][t]+q[d])*v[d]; softmax
        // (max-free: |e| <= sum|v| ~ 10, exp safe in fp32)
        // mlen-adaptive mapping: short rows use 64 chunks x 16 d-parts so
        // ALL 1024 threads stream keysT (old mapping idled >= half).
        if (msmall){
            const int tc   = tid & 63;     // 64 chunks x 8 t  (t < 512)
            const int part = tid >> 6;     // 16 parts x 16 d
            float acc0=0.f,acc1=0.f,acc2=0.f,acc3=0.f,acc4=0.f,acc5=0.f,acc6=0.f,acc7=0.f;
            if (tc * 8 < mlen){
                const unsigned short* kp = p.keysT + (((size_t)b) << 18)
                                         + ((size_t)(part * 16) << 10) + tc * 8;
                #pragma unroll 16
                for (int dd = 0; dd < 16; dd++){
                    uint4 kv = *(const uint4*)(kp + ((size_t)dd << 10));
                    int d = part * 16 + dd;
                    float qd = q_l[d], vd = v_l[d];
                    acc0 = fmaf(ftanh(__uint_as_float(kv.x << 16)         + qd), vd, acc0);
                    acc1 = fmaf(ftanh(__uint_as_float(kv.x & 0xffff0000u) + qd), vd, acc1);
                    acc2 = fmaf(ftanh(__uint_as_float(kv.y << 16)         + qd), vd, acc2);
                    acc3 = fmaf(ftanh(__uint_as_float(kv.y & 0xffff0000u) + qd), vd, acc3);
                    acc4 = fmaf(ftanh(__uint_as_float(kv.z << 16)         + qd), vd, acc4);
                    acc5 = fmaf(ftanh(__uint_as_float(kv.z & 0xffff0000u) + qd), vd, acc5);
                    acc6 = fmaf(ftanh(__uint_as_float(kv.w << 16)         + qd), vd, acc6);
                    acc7 = fmaf(ftanh(__uint_as_float(kv.w & 0xffff0000u) + qd), vd, acc7);
                }
            }
            float4* s4 = (float4*)(scr + part * 512 + tc * 8);
            s4[0] = float4{acc0, acc1, acc2, acc3};
            s4[1] = float4{acc4, acc5, acc6, acc7};
        } else {
            const int tc   = tid & 127;    // 128 chunks x 8 t
            const int part = tid >> 7;     // 8 parts x 32 d
            float acc0=0.f,acc1=0.f,acc2=0.f,acc3=0.f,acc4=0.f,acc5=0.f,acc6=0.f,acc7=0.f;
            if (tc * 8 < mlen){
                const unsigned short* kp = p.keysT + (((size_t)b) << 18)
                                         + ((size_t)(part * 32) << 10) + tc * 8;
                #pragma unroll 16
                for (int dd = 0; dd < 32; dd++){
                    uint4 kv = *(const uint4*)(kp + ((size_t)dd << 10));
                    int d = part * 32 + dd;
                    float qd = q_l[d], vd = v_l[d];
                    acc0 = fmaf(ftanh(__uint_as_float(kv.x << 16)         + qd), vd, acc0);
                    acc1 = fmaf(ftanh(__uint_as_float(kv.x & 0xffff0000u) + qd), vd, acc1);
                    acc2 = fmaf(ftanh(__uint_as_float(kv.y << 16)         + qd), vd, acc2);
                    acc3 = fmaf(ftanh(__uint_as_float(kv.y & 0xffff0000u) + qd), vd, acc3);
                    acc4 = fmaf(ftanh(__uint_as_float(kv.z << 16)         + qd), vd, acc4);
                    acc5 = fmaf(ftanh(__uint_as_float(kv.z & 0xffff0000u) + qd), vd, acc5);
                    acc6 = fmaf(ftanh(__uint_as_float(kv.w << 16)         + qd), vd, acc6);
                    acc7 = fmaf(ftanh(__uint_as_float(kv.w & 0xffff0000u) + qd), vd, acc7);
                }
            }
            float4* s4 = (float4*)(scr + part * 1024 + tc * 8);
            s4[0] = float4{acc0, acc1, acc2, acc3};
            s4[1] = float4{acc4, acc5, acc6, acc7};
        }
        __syncthreads();
        float av = 0.f;
        if (tid < mlen){
            float s8 = 0.f;
            if (msmall){
                #pragma unroll
                for (int pp = 0; pp < 16; pp++) s8 += scr[pp * 512 + tid];
            } else {
                #pragma unroll
                for (int pp = 0; pp < 8; pp++) s8 += scr[pp * 1024 + tid];
            }
            av = __expf(s8);
        }
        {   // block sum: per-wave shuffle -> 16 LDS -> broadcast sum
            float ws = av;
            #pragma unroll
            for (int off = 32; off; off >>= 1) ws += __shfl_xor(ws, off, 64);
            if ((tid & 63) == 0) red[tid >> 6] = ws;
        }
        __syncthreads();
        {
            float tot = 0.f;
            #pragma unroll
            for (int i = 0; i < 16; i++) tot += red[i];
            float alpha = av * __builtin_amdgcn_rcpf(tot);
            e_l[tid] = alpha;
            __builtin_nontemporal_store(alpha,
                &p.out[ALPHA_OFF + (size_t)s * 131072 + ((size_t)b << 10) + tid]);
        }
        __syncthreads();

        // ---- P7: context ctx[d] = sum_t alpha[t]*enc[t][d]; fills xa/xd, wp
        {
            const int dc = tid & 31;
            const int tp = tid >> 5;
            float acc0=0.f,acc1=0.f,acc2=0.f,acc3=0.f,acc4=0.f,acc5=0.f,acc6=0.f,acc7=0.f;
            const unsigned short* er = p.encb + (((size_t)b) << 18) + dc * 8;
            #pragma unroll 8
            for (int t = tp; t < mlen; t += 32){
                uint4 ev4 = *(const uint4*)(er + ((size_t)t << 8));
                float al = e_l[t];
                acc0 = fmaf(al, __uint_as_float(ev4.x << 16),         acc0);
                acc1 = fmaf(al, __uint_as_float(ev4.x & 0xffff0000u), acc1);
                acc2 = fmaf(al, __uint_as_float(ev4.y << 16),         acc2);
                acc3 = fmaf(al, __uint_as_float(ev4.y & 0xffff0000u), acc3);
                acc4 = fmaf(al, __uint_as_float(ev4.z << 16),         acc4);
                acc5 = fmaf(al, __uint_as_float(ev4.z & 0xffff0000u), acc5);
                acc6 = fmaf(al, __uint_as_float(ev4.w << 16),         acc6);
                acc7 = fmaf(al, __uint_as_float(ev4.w & 0xffff0000u), acc7);
            }
            float4* s4 = (float4*)(scr + tp * 256 + dc * 8);
            s4[0] = float4{acc0, acc1, acc2, acc3};
            s4[1] = float4{acc4, acc5, acc6, acc7};
        }
        __syncthreads();
        if (tid < 256){
            float cs = red_parts<256,32>(scr, tid);
            xa[tid] = cs;                        // ctx for next step's P3
            xd[256 + tid] = cs + stylel[tid];    // wctx for P8
            float wpv = astylel[tid] * __builtin_amdgcn_rcpf(fabsf(cs) + astylel[tid]);
            #pragma unroll
            for (int off = 32; off; off >>= 1) wpv += __shfl_xor(wpv, off, 64);
            if ((tid & 63) == 0) atomicAdd(&p.wacc[s], wpv);
        }
        __syncthreads();

        // ---- P8: dec_in = [h_att, wctx] @ deci_W + b ----
        gemv_part<512, 256, 32>(W + OFF_DECI_W, xd, scr, tid);
        __syncthreads();
        if (tid < 256){
            float d = p.deci_b[tid] + red_parts<256,32>(scr, tid);
            dci[tid] = d;
            xg[tid] = d; xg[256 + tid] = h1[tid];
        }
        __syncthreads();

        // ---- P9: dec1 phase A ----
        gemv_part<512, 512, 16>(W + OFF_DEC1_WG, xg, scr,  tid);
        gemv_part<256, 256, 32>(W + OFF_DEC1_WC, xg, scr2, tid);   // x-part only
        __syncthreads();
        if (tid < 512){
            float g = fsig(p.dec1_bg[tid] + red_parts<512,16>(scr, tid));
            g_l[tid] = g;
            if (tid < 256) xr[tid] = g * h1[tid];
        } else if (tid < 768){
            int n = tid - 512;
            cx_l[n] = p.dec1_bc[n] + red_parts<256,32>(scr2, n);
        }
        __syncthreads();

        // ---- P10: dec1 phase B ----
        gemv_part<256, 256, 32>(W + OFF_DEC1_WCH, xr, scr, tid);
        __syncthreads();
        if (tid < 256){
            float c = ftanh(cx_l[tid] + red_parts<256,32>(scr, tid));
            float u = g_l[256 + tid];
            float hn = u * h1[tid] + (1.f - u) * c;
            h1[tid] = hn;
            float o1 = hn + dci[tid];
            o1_l[tid] = o1;
            xg[tid] = o1; xg[256 + tid] = h2[tid];
        }
        __syncthreads();

        // ---- P11: dec2 phase A ----
        gemv_part<512, 512, 16>(W + OFF_DEC2_WG, xg, scr,  tid);
        gemv_part<256, 256, 32>(W + OFF_DEC2_WC, xg, scr2, tid);
        __syncthreads();
        if (tid < 512){
            float g = fsig(p.dec2_bg[tid] + red_parts<512,16>(scr, tid));
            g_l[tid] = g;
            if (tid < 256) xr[tid] = g * h2[tid];
        } else if (tid < 768){
            int n = tid - 512;
            cx_l[n] = p.dec2_bc[n] + red_parts<256,32>(scr2, n);
        }
        __syncthreads();

        // ---- P12: dec2 phase B ----
        gemv_part<256, 256, 32>(W + OFF_DEC2_WCH, xr, scr, tid);
        __syncthreads();
        if (tid < 256){
            float c = ftanh(cx_l[tid] + red_parts<256,32>(scr, tid));
            float u = g_l[256 + tid];
            float hn = u * h2[tid] + (1.f - u) * c;
            h2[tid] = hn;
            o2_l[tid] = hn + o1_l[tid];
        }
        __syncthreads();

        // ---- P13: output dense (256 -> 400 via padded 512) ----
        gemv_part<256, 512, 16>(W + OFF_OUT_WP, o2_l, scr, tid);
        __syncthreads();
        if (tid < 400){
            float val = p.out_b[tid] + red_parts<512,16>(scr, tid);
            __builtin_nontemporal_store(val,
                &p.out[(size_t)b * 100000 + (size_t)s * 400 + tid]);
            if (tid >= 320) last_o[tid - 320] = val;
        }
        __syncthreads();
    }
}

// ---------------- K3: finalize weight_pers ----------------------------------
__global__ void k_final(const float* __restrict__ wacc, float* __restrict__ out)
{
    int i = threadIdx.x;
    if (i < TDEC) out[WP_OFF + i] = wacc[i] * (1.0f / 32768.0f);
}

// ---------------------------------------------------------------------------
extern "C" void kernel_launch(void* const* d_in, const int* in_sizes, int n_in,
                              void* d_out, int out_size, void* d_ws, size_t ws_size,
                              hipStream_t stream)
{
    const float* enc        = (const float*)d_in[0];
    const int*   imask      = (const int*)  d_in[1];
    const float* inp_att    = (const float*)d_in[2];
    const float* style_tok  = (const float*)d_in[3];
    const float* pre_W1     = (const float*)d_in[4];
    const float* pre_b1     = (const float*)d_in[5];
    const float* pre_W2     = (const float*)d_in[6];
    const float* pre_b2     = (const float*)d_in[7];
    const float* att_Wg     = (const float*)d_in[8];
    const float* att_bg     = (const float*)d_in[9];
    const float* att_Wc     = (const float*)d_in[10];
    const float* att_bc     = (const float*)d_in[11];
    const float* attn_Wk    = (const float*)d_in[12];
    const float* attn_bk    = (const float*)d_in[13];
    const float* attn_Wq    = (const float*)d_in[14];
    const float* attn_bq    = (const float*)d_in[15];
    const float* attn_v     = (const float*)d_in[16];
    const float* deci_W     = (const float*)d_in[17];
    const float* deci_b     = (const float*)d_in[18];
    const float* dec1_Wg    = (const float*)d_in[19];
    const float* dec1_bg    = (const float*)d_in[20];
    const float* dec1_Wc    = (const float*)d_in[21];
    const float* dec1_bc    = (const float*)d_in[22];
    const float* dec2_Wg    = (const float*)d_in[23];
    const float* dec2_bg    = (const float*)d_in[24];
    const float* dec2_Wc    = (const float*)d_in[25];
    const float* dec2_bc    = (const float*)d_in[26];
    const float* out_W      = (const float*)d_in[27];
    const float* out_b      = (const float*)d_in[28];

    float*          wacc  = (float*)((char*)d_ws + WS_WACC_B);
    f16*            wgt   = (f16*)  ((char*)d_ws + WS_WGT_B);
    unsigned short* keysT = (unsigned short*)((char*)d_ws + WS_KEYS_B);
    unsigned short* encb  = (unsigned short*)((char*)d_ws + WS_ENC_B);
    float* out = (float*)d_out;

    hipMemsetAsync(d_ws, 0, 1024, stream);

    // ---- weight conversions (f16, row-major — byte-identical addresses) ----
    auto cvt = [&](const float* src, size_t off, int n){
        k_cvt_flat16<<<(n + 255) / 256, 256, 0, stream>>>(src, wgt + off, n);
    };
    cvt(pre_W1,  OFF_PRE_W1,   80 * 256);
    cvt(pre_W2,  OFF_PRE_W2,  256 * 128);
    cvt(att_Wg,  OFF_ATT_WG,  640 * 512);
    cvt(att_Wc,  OFF_ATT_WC,  640 * 256);
    cvt(attn_Wq, OFF_ATTN_WQ, 256 * 256);
    cvt(deci_W,  OFF_DECI_W,  512 * 256);
    cvt(dec1_Wg, OFF_DEC1_WG, 512 * 512);
    cvt(dec1_Wc, OFF_DEC1_WC, 512 * 256);
    cvt(dec2_Wg, OFF_DEC2_WG, 512 * 512);
    cvt(dec2_Wc, OFF_DEC2_WC, 512 * 256);
    k_cvt_pad16<<<(256 * 512) / 256, 256, 0, stream>>>(out_W, wgt + OFF_OUT_WP);

    // ---- enc -> bf16 ----
    k_cvt_flat<<<(33554432 + 255) / 256, 256, 0, stream>>>(enc, encb, 33554432);

    // ---- keys (transposed bf16) ----
    k_keys<<<2048, 256, 0, stream>>>(enc, attn_Wk, attn_bk, keysT);

    KParams kp{imask, inp_att, style_tok,
               pre_b1, pre_b2, att_bg, att_bc, attn_bq, attn_v,
               deci_b, dec1_bg, dec1_bc, dec2_bg, dec2_bc, out_b,
               wgt, keysT, encb, wacc, out};
    k_main<<<BATCH, 1024, 0, stream>>>(kp);

    k_final<<<1, 256, 0, stream>>>(wacc, out);
}